// Round 1
// baseline (6660.967 us; speedup 1.0000x reference)
//
#include <hip/hip_runtime.h>
#include <hip/hip_bf16.h>

constexpr int DOUT = 256;

// ---------------- degree ----------------
__global__ __launch_bounds__(256) void k_deg_count(const int* __restrict__ dst,
                                                   int* __restrict__ cnt, int E) {
  int t = blockIdx.x * blockDim.x + threadIdx.x;
  if (t < E) atomicAdd(&cnt[dst[t]], 1);
}

__global__ __launch_bounds__(256) void k_deg_inv(const int* __restrict__ cnt,
                                                 float* __restrict__ dinv, int n) {
  int t = blockIdx.x * blockDim.x + threadIdx.x;
  if (t < n) dinv[t] = 1.0f / (float)cnt[t];  // self loops guarantee >=1
}

__global__ __launch_bounds__(256) void k_gcnt(const int* __restrict__ gid,
                                              int* __restrict__ cnt, int n) {
  int t = blockIdx.x * blockDim.x + threadIdx.x;
  if (t < n) atomicAdd(&cnt[gid[t]], 1);
}

// ---------------- scatter-add aggregation ----------------
// thread t handles one float4 chunk of one edge
__global__ __launch_bounds__(256) void k_scatter(const float* __restrict__ h,
                                                 const int* __restrict__ src,
                                                 const int* __restrict__ dst,
                                                 float* __restrict__ agg,
                                                 int E, int Din) {
  const int per = Din >> 2;  // float4 chunks per row
  long long t = (long long)blockIdx.x * blockDim.x + threadIdx.x;
  if (t >= (long long)E * per) return;
  int e = (int)(t / per);
  int c = (int)(t % per);
  int s = src[e], d = dst[e];
  const float4 v = *(const float4*)(h + (size_t)s * Din + c * 4);
  float* p = agg + (size_t)d * Din + c * 4;
  atomicAdd(p + 0, v.x);
  atomicAdd(p + 1, v.y);
  atomicAdd(p + 2, v.z);
  atomicAdd(p + 3, v.w);
}

// ---------------- fused dual GEMM: out = h@Ws + (agg*dinv)@Wn + b ----------------
// A = [h | agg*dinv] (N x 2*DIN), B = [Ws ; Wn] (2*DIN x 256)
template <int DIN>
__global__ __launch_bounds__(256) void k_sage_gemm(
    const float* __restrict__ h, const float* __restrict__ agg,
    const float* __restrict__ dinv, const float* __restrict__ Ws,
    const float* __restrict__ Wn, const float* __restrict__ bias,
    float* __restrict__ out, int n) {
  constexpr int K = 2 * DIN;
  __shared__ float As[16][65];  // [k][m]
  __shared__ float Bs[16][68];  // [k][n]
  const int tid = threadIdx.x;
  const int tx = tid & 15, ty = tid >> 4;
  const int m0 = blockIdx.x * 64, n0 = blockIdx.y * 64;
  const int a_row = tid >> 2, a_kq = (tid & 3) * 4;  // A tile load mapping
  const int b_k = tid >> 4, b_cq = (tid & 15) * 4;   // B tile load mapping
  float acc[4][4] = {};

  for (int k0 = 0; k0 < K; k0 += 16) {
    // load A tile (64 rows x 16 k), transposed into As[k][m]
    {
      int grow = m0 + a_row;
      float4 va = make_float4(0.f, 0.f, 0.f, 0.f);
      if (grow < n) {
        int k = k0 + a_kq;
        if (k < DIN) {
          va = *(const float4*)(h + (size_t)grow * DIN + k);
        } else {
          va = *(const float4*)(agg + (size_t)grow * DIN + (k - DIN));
          float s = dinv[grow];
          va.x *= s; va.y *= s; va.z *= s; va.w *= s;
        }
      }
      As[a_kq + 0][a_row] = va.x;
      As[a_kq + 1][a_row] = va.y;
      As[a_kq + 2][a_row] = va.z;
      As[a_kq + 3][a_row] = va.w;
    }
    // load B tile (16 k x 64 cols)
    {
      int k = k0 + b_k;
      const float* Wp = (k < DIN) ? (Ws + (size_t)k * DOUT)
                                  : (Wn + (size_t)(k - DIN) * DOUT);
      *(float4*)(&Bs[b_k][b_cq]) = *(const float4*)(Wp + n0 + b_cq);
    }
    __syncthreads();
#pragma unroll
    for (int k = 0; k < 16; ++k) {
      float a_[4], b_[4];
#pragma unroll
      for (int i = 0; i < 4; i++) a_[i] = As[k][ty * 4 + i];
#pragma unroll
      for (int j = 0; j < 4; j++) b_[j] = Bs[k][tx * 4 + j];
#pragma unroll
      for (int i = 0; i < 4; i++)
#pragma unroll
        for (int j = 0; j < 4; j++) acc[i][j] = fmaf(a_[i], b_[j], acc[i][j]);
    }
    __syncthreads();
  }
#pragma unroll
  for (int i = 0; i < 4; i++) {
    int r = m0 + ty * 4 + i;
    if (r >= n) break;
#pragma unroll
    for (int j = 0; j < 4; j++) {
      int c = n0 + tx * 4 + j;
      out[(size_t)r * DOUT + c] = acc[i][j] + bias[c];
    }
  }
}

// ---------------- LayerNorm + ELU (in place), one wave per row ----------------
__global__ __launch_bounds__(256) void k_ln_elu(float* __restrict__ x,
                                                const float* __restrict__ g,
                                                const float* __restrict__ be,
                                                int n) {
  int wave = threadIdx.x >> 6;
  int lane = threadIdx.x & 63;
  int row = blockIdx.x * 4 + wave;
  if (row >= n) return;
  float* p = x + (size_t)row * DOUT + lane * 4;
  float4 v = *(const float4*)p;
  float s = v.x + v.y + v.z + v.w;
#pragma unroll
  for (int o = 32; o > 0; o >>= 1) s += __shfl_xor(s, o);
  float mean = s * (1.0f / 256.0f);
  float dx = v.x - mean, dy = v.y - mean, dz = v.z - mean, dw = v.w - mean;
  float q = dx * dx + dy * dy + dz * dz + dw * dw;
#pragma unroll
  for (int o = 32; o > 0; o >>= 1) q += __shfl_xor(q, o);
  float rstd = rsqrtf(q * (1.0f / 256.0f) + 1e-5f);
  int c = lane * 4;
  float4 gg = *(const float4*)(g + c);
  float4 bb = *(const float4*)(be + c);
  float o0 = dx * rstd * gg.x + bb.x;
  float o1 = dy * rstd * gg.y + bb.y;
  float o2 = dz * rstd * gg.z + bb.z;
  float o3 = dw * rstd * gg.w + bb.w;
  o0 = o0 > 0.f ? o0 : expm1f(o0);
  o1 = o1 > 0.f ? o1 : expm1f(o1);
  o2 = o2 > 0.f ? o2 : expm1f(o2);
  o3 = o3 > 0.f ? o3 : expm1f(o3);
  *(float4*)p = make_float4(o0, o1, o2, o3);
}

// ---------------- per-graph mean readout ----------------
__global__ __launch_bounds__(256) void k_readout(const float* __restrict__ h,
                                                 const int* __restrict__ gid,
                                                 float* __restrict__ hg, int n) {
  int start = blockIdx.x * 64;
  int end = min(start + 64, n);
  int c = threadIdx.x;
  float acc = 0.f;
  int cur = gid[start];
  for (int i = start; i < end; ++i) {
    int g = gid[i];
    if (g != cur) {
      atomicAdd(&hg[(size_t)cur * DOUT + c], acc);
      acc = 0.f;
      cur = g;
    }
    acc += h[(size_t)i * DOUT + c];
  }
  atomicAdd(&hg[(size_t)cur * DOUT + c], acc);
}

__global__ __launch_bounds__(256) void k_hg_scale(float* __restrict__ hg,
                                                  const int* __restrict__ cnt,
                                                  int total) {
  int t = blockIdx.x * blockDim.x + threadIdx.x;
  if (t < total) hg[t] *= 1.0f / (float)cnt[t >> 8];
}

extern "C" void kernel_launch(void* const* d_in, const int* in_sizes, int n_in,
                              void* d_out, int out_size, void* d_ws, size_t ws_size,
                              hipStream_t stream) {
  const float* feat = (const float*)d_in[0];
  const int* esrc = (const int*)d_in[1];
  const int* edst = (const int*)d_in[2];
  const int* gid = (const int*)d_in[3];
  const float* Ws0 = (const float*)d_in[4];
  const float* Wn0 = (const float*)d_in[5];
  const float* b0 = (const float*)d_in[6];
  const float* g0 = (const float*)d_in[7];
  const float* be0 = (const float*)d_in[8];
  const float* Ws1 = (const float*)d_in[9];
  const float* Wn1 = (const float*)d_in[10];
  const float* b1 = (const float*)d_in[11];
  const float* g1 = (const float*)d_in[12];
  const float* be1 = (const float*)d_in[13];
  const float* Ws2 = (const float*)d_in[14];
  const float* Wn2 = (const float*)d_in[15];
  const float* b2 = (const float*)d_in[16];
  const float* g2 = (const float*)d_in[17];
  const float* be2 = (const float*)d_in[18];

  const int E = in_sizes[1];
  const int n = in_sizes[3];
  const int DIN0 = in_sizes[0] / n;  // 128
  const int Gn = (out_size - n * DOUT) / DOUT;  // 16

  // workspace layout
  char* ws = (char*)d_ws;
  size_t off = 0;
  auto alloc = [&](size_t bytes) -> void* {
    void* p = ws + off;
    off += (bytes + 255) & ~(size_t)255;
    return p;
  };
  int* deg_cnt = (int*)alloc((size_t)n * 4);
  float* dinv = (float*)alloc((size_t)n * 4);
  int* gcnt = (int*)alloc((size_t)Gn * 4);
  float* bufA = (float*)alloc((size_t)n * DOUT * 4);
  float* bufB = (float*)alloc((size_t)n * DOUT * 4);

  float* out_h = (float*)d_out;
  float* out_hg = out_h + (size_t)n * DOUT;

  hipMemsetAsync(deg_cnt, 0, (size_t)n * 4, stream);
  hipMemsetAsync(gcnt, 0, (size_t)Gn * 4, stream);
  hipMemsetAsync(out_hg, 0, (size_t)Gn * DOUT * 4, stream);

  k_deg_count<<<(E + 255) / 256, 256, 0, stream>>>(edst, deg_cnt, E);
  k_deg_inv<<<(n + 255) / 256, 256, 0, stream>>>(deg_cnt, dinv, n);
  k_gcnt<<<(n + 255) / 256, 256, 0, stream>>>(gid, gcnt, n);

  dim3 gemm_grid((n + 63) / 64, DOUT / 64);

  // ---- layer 0: h = feat (DIN0=128), agg->bufA, out->bufB ----
  hipMemsetAsync(bufA, 0, (size_t)n * DIN0 * 4, stream);
  {
    long long tot = (long long)E * (DIN0 / 4);
    k_scatter<<<(int)((tot + 255) / 256), 256, 0, stream>>>(feat, esrc, edst,
                                                            bufA, E, DIN0);
  }
  k_sage_gemm<128><<<gemm_grid, 256, 0, stream>>>(feat, bufA, dinv, Ws0, Wn0,
                                                  b0, bufB, n);
  k_ln_elu<<<(n + 3) / 4, 256, 0, stream>>>(bufB, g0, be0, n);

  // ---- layer 1: h = bufB, agg->bufA, out->out_h ----
  hipMemsetAsync(bufA, 0, (size_t)n * DOUT * 4, stream);
  {
    long long tot = (long long)E * (DOUT / 4);
    k_scatter<<<(int)((tot + 255) / 256), 256, 0, stream>>>(bufB, esrc, edst,
                                                            bufA, E, DOUT);
  }
  k_sage_gemm<256><<<gemm_grid, 256, 0, stream>>>(bufB, bufA, dinv, Ws1, Wn1,
                                                  b1, out_h, n);
  k_ln_elu<<<(n + 3) / 4, 256, 0, stream>>>(out_h, g1, be1, n);

  // ---- layer 2: h = out_h, agg->bufA, out->bufB ----
  hipMemsetAsync(bufA, 0, (size_t)n * DOUT * 4, stream);
  {
    long long tot = (long long)E * (DOUT / 4);
    k_scatter<<<(int)((tot + 255) / 256), 256, 0, stream>>>(out_h, esrc, edst,
                                                            bufA, E, DOUT);
  }
  k_sage_gemm<256><<<gemm_grid, 256, 0, stream>>>(out_h, bufA, dinv, Ws2, Wn2,
                                                  b2, bufB, n);
  k_ln_elu<<<(n + 3) / 4, 256, 0, stream>>>(bufB, g2, be2, n);

  // ---- readout from bufB; copy final h to d_out ----
  k_readout<<<(n + 63) / 64, 256, 0, stream>>>(bufB, gid, out_hg, n);
  k_hg_scale<<<(Gn * DOUT + 255) / 256, 256, 0, stream>>>(out_hg, gcnt,
                                                          Gn * DOUT);
  hipMemcpyAsync(out_h, bufB, (size_t)n * DOUT * 4, hipMemcpyDeviceToDevice,
                 stream);
}

// Round 2
// 1520.207 us; speedup vs baseline: 4.3816x; 4.3816x over previous
//
#include <hip/hip_runtime.h>
#include <hip/hip_bf16.h>

constexpr int DOUT = 256;

// ---------------- degree / counts ----------------
__global__ __launch_bounds__(256) void k_deg_count(const int* __restrict__ dst,
                                                   int* __restrict__ cnt, int E) {
  int t = blockIdx.x * blockDim.x + threadIdx.x;
  if (t < E) atomicAdd(&cnt[dst[t]], 1);
}

__global__ __launch_bounds__(256) void k_deg_inv(const int* __restrict__ cnt,
                                                 float* __restrict__ dinv, int n) {
  int t = blockIdx.x * blockDim.x + threadIdx.x;
  if (t < n) dinv[t] = 1.0f / (float)cnt[t];  // self loops guarantee >=1
}

__global__ __launch_bounds__(256) void k_gcnt(const int* __restrict__ gid,
                                              int* __restrict__ cnt, int n) {
  int t = blockIdx.x * blockDim.x + threadIdx.x;
  if (t < n) atomicAdd(&cnt[gid[t]], 1);
}

// ---------------- CSR build: 3-kernel exclusive scan + fill ----------------
__global__ __launch_bounds__(256) void k_scan1(const int* __restrict__ deg,
                                               int* __restrict__ part, int n) {
  int i = blockIdx.x * 256 + threadIdx.x;
  int v = (i < n) ? deg[i] : 0;
#pragma unroll
  for (int o = 32; o > 0; o >>= 1) v += __shfl_xor(v, o);
  __shared__ int s[4];
  int wave = threadIdx.x >> 6, lane = threadIdx.x & 63;
  if (lane == 0) s[wave] = v;
  __syncthreads();
  if (threadIdx.x == 0) part[blockIdx.x] = s[0] + s[1] + s[2] + s[3];
}

__global__ __launch_bounds__(256) void k_scan2(int* __restrict__ part, int nb) {
  __shared__ int s[256];
  int t = threadIdx.x;
  int v = (t < nb) ? part[t] : 0;
  s[t] = v;
  __syncthreads();
  for (int o = 1; o < 256; o <<= 1) {
    int u = (t >= o) ? s[t - o] : 0;
    __syncthreads();
    s[t] += u;
    __syncthreads();
  }
  int excl = (t == 0) ? 0 : s[t - 1];
  if (t < nb) part[t] = excl;
}

__global__ __launch_bounds__(256) void k_scan3(const int* __restrict__ deg,
                                               const int* __restrict__ part,
                                               int* __restrict__ rp,
                                               int* __restrict__ cur, int n) {
  __shared__ int s[256];
  int t = threadIdx.x;
  int i = blockIdx.x * 256 + t;
  int v = (i < n) ? deg[i] : 0;
  s[t] = v;
  __syncthreads();
  for (int o = 1; o < 256; o <<= 1) {
    int u = (t >= o) ? s[t - o] : 0;
    __syncthreads();
    s[t] += u;
    __syncthreads();
  }
  int incl = s[t];
  int excl = incl - v;
  int base = part[blockIdx.x];
  if (i < n) {
    rp[i] = base + excl;
    cur[i] = base + excl;
  }
  if (i == n - 1) rp[n] = base + incl;
}

__global__ __launch_bounds__(256) void k_fill(const int* __restrict__ src,
                                              const int* __restrict__ dst,
                                              int* __restrict__ cur,
                                              int* __restrict__ col, int E) {
  int e = blockIdx.x * 256 + threadIdx.x;
  if (e < E) {
    int p = atomicAdd(&cur[dst[e]], 1);
    col[p] = src[e];
  }
}

// ---------------- CSR gather aggregation: agg[i] = dinv[i] * sum h[col[j]] ----
template <int DIN>
__global__ __launch_bounds__(256) void k_gather(const float* __restrict__ h,
                                                const int* __restrict__ rp,
                                                const int* __restrict__ col,
                                                const float* __restrict__ dinv,
                                                float* __restrict__ agg, int n) {
  int wave = threadIdx.x >> 6, lane = threadIdx.x & 63;
  int node = blockIdx.x * 4 + wave;
  if (node >= n) return;
  int beg = rp[node], end = rp[node + 1];
  float s = dinv[node];
  if constexpr (DIN == 256) {
    const float* base = h + lane * 4;
    float4 acc = make_float4(0.f, 0.f, 0.f, 0.f);
    int j = beg;
    for (; j + 1 < end; j += 2) {
      int c0 = col[j], c1 = col[j + 1];
      float4 v0 = *(const float4*)(base + (size_t)c0 * DIN);
      float4 v1 = *(const float4*)(base + (size_t)c1 * DIN);
      acc.x += v0.x + v1.x;
      acc.y += v0.y + v1.y;
      acc.z += v0.z + v1.z;
      acc.w += v0.w + v1.w;
    }
    if (j < end) {
      float4 v0 = *(const float4*)(base + (size_t)col[j] * DIN);
      acc.x += v0.x; acc.y += v0.y; acc.z += v0.z; acc.w += v0.w;
    }
    float4 o = make_float4(acc.x * s, acc.y * s, acc.z * s, acc.w * s);
    *(float4*)(agg + (size_t)node * DIN + lane * 4) = o;
  } else {  // DIN == 128: float2 per lane
    const float* base = h + lane * 2;
    float2 acc = make_float2(0.f, 0.f);
    int j = beg;
    for (; j + 1 < end; j += 2) {
      int c0 = col[j], c1 = col[j + 1];
      float2 v0 = *(const float2*)(base + (size_t)c0 * DIN);
      float2 v1 = *(const float2*)(base + (size_t)c1 * DIN);
      acc.x += v0.x + v1.x;
      acc.y += v0.y + v1.y;
    }
    if (j < end) {
      float2 v0 = *(const float2*)(base + (size_t)col[j] * DIN);
      acc.x += v0.x; acc.y += v0.y;
    }
    *(float2*)(agg + (size_t)node * DIN + lane * 2) =
        make_float2(acc.x * s, acc.y * s);
  }
}

// ---------------- fused dual GEMM: out = h@Ws + agg@Wn + b ----------------
template <int DIN>
__global__ __launch_bounds__(256) void k_sage_gemm(
    const float* __restrict__ h, const float* __restrict__ agg,
    const float* __restrict__ Ws, const float* __restrict__ Wn,
    const float* __restrict__ bias, float* __restrict__ out, int n) {
  constexpr int K = 2 * DIN;
  __shared__ float As[16][65];  // [k][m]
  __shared__ float Bs[16][68];  // [k][n]
  const int tid = threadIdx.x;
  const int tx = tid & 15, ty = tid >> 4;
  const int m0 = blockIdx.x * 64, n0 = blockIdx.y * 64;
  const int a_row = tid >> 2, a_kq = (tid & 3) * 4;
  const int b_k = tid >> 4, b_cq = (tid & 15) * 4;
  float acc[4][4] = {};

  for (int k0 = 0; k0 < K; k0 += 16) {
    {
      int grow = m0 + a_row;
      float4 va = make_float4(0.f, 0.f, 0.f, 0.f);
      if (grow < n) {
        int k = k0 + a_kq;
        if (k < DIN)
          va = *(const float4*)(h + (size_t)grow * DIN + k);
        else
          va = *(const float4*)(agg + (size_t)grow * DIN + (k - DIN));
      }
      As[a_kq + 0][a_row] = va.x;
      As[a_kq + 1][a_row] = va.y;
      As[a_kq + 2][a_row] = va.z;
      As[a_kq + 3][a_row] = va.w;
    }
    {
      int k = k0 + b_k;
      const float* Wp = (k < DIN) ? (Ws + (size_t)k * DOUT)
                                  : (Wn + (size_t)(k - DIN) * DOUT);
      *(float4*)(&Bs[b_k][b_cq]) = *(const float4*)(Wp + n0 + b_cq);
    }
    __syncthreads();
#pragma unroll
    for (int k = 0; k < 16; ++k) {
      float a_[4], b_[4];
#pragma unroll
      for (int i = 0; i < 4; i++) a_[i] = As[k][ty * 4 + i];
#pragma unroll
      for (int j = 0; j < 4; j++) b_[j] = Bs[k][tx * 4 + j];
#pragma unroll
      for (int i = 0; i < 4; i++)
#pragma unroll
        for (int j = 0; j < 4; j++) acc[i][j] = fmaf(a_[i], b_[j], acc[i][j]);
    }
    __syncthreads();
  }
#pragma unroll
  for (int i = 0; i < 4; i++) {
    int r = m0 + ty * 4 + i;
    if (r >= n) break;
#pragma unroll
    for (int j = 0; j < 4; j++) {
      int c = n0 + tx * 4 + j;
      out[(size_t)r * DOUT + c] = acc[i][j] + bias[c];
    }
  }
}

// ---------------- LayerNorm + ELU (in place), one wave per row ----------------
__global__ __launch_bounds__(256) void k_ln_elu(float* __restrict__ x,
                                                const float* __restrict__ g,
                                                const float* __restrict__ be,
                                                int n) {
  int wave = threadIdx.x >> 6;
  int lane = threadIdx.x & 63;
  int row = blockIdx.x * 4 + wave;
  if (row >= n) return;
  float* p = x + (size_t)row * DOUT + lane * 4;
  float4 v = *(const float4*)p;
  float s = v.x + v.y + v.z + v.w;
#pragma unroll
  for (int o = 32; o > 0; o >>= 1) s += __shfl_xor(s, o);
  float mean = s * (1.0f / 256.0f);
  float dx = v.x - mean, dy = v.y - mean, dz = v.z - mean, dw = v.w - mean;
  float q = dx * dx + dy * dy + dz * dz + dw * dw;
#pragma unroll
  for (int o = 32; o > 0; o >>= 1) q += __shfl_xor(q, o);
  float rstd = rsqrtf(q * (1.0f / 256.0f) + 1e-5f);
  int c = lane * 4;
  float4 gg = *(const float4*)(g + c);
  float4 bb = *(const float4*)(be + c);
  float o0 = dx * rstd * gg.x + bb.x;
  float o1 = dy * rstd * gg.y + bb.y;
  float o2 = dz * rstd * gg.z + bb.z;
  float o3 = dw * rstd * gg.w + bb.w;
  o0 = o0 > 0.f ? o0 : expm1f(o0);
  o1 = o1 > 0.f ? o1 : expm1f(o1);
  o2 = o2 > 0.f ? o2 : expm1f(o2);
  o3 = o3 > 0.f ? o3 : expm1f(o3);
  *(float4*)p = make_float4(o0, o1, o2, o3);
}

// ---------------- per-graph mean readout ----------------
__global__ __launch_bounds__(256) void k_readout(const float* __restrict__ h,
                                                 const int* __restrict__ gid,
                                                 float* __restrict__ hg, int n) {
  int start = blockIdx.x * 64;
  int end = min(start + 64, n);
  int c = threadIdx.x;
  float acc = 0.f;
  int cur = gid[start];
  for (int i = start; i < end; ++i) {
    int g = gid[i];
    if (g != cur) {
      atomicAdd(&hg[(size_t)cur * DOUT + c], acc);
      acc = 0.f;
      cur = g;
    }
    acc += h[(size_t)i * DOUT + c];
  }
  atomicAdd(&hg[(size_t)cur * DOUT + c], acc);
}

__global__ __launch_bounds__(256) void k_hg_scale(float* __restrict__ hg,
                                                  const int* __restrict__ cnt,
                                                  int total) {
  int t = blockIdx.x * blockDim.x + threadIdx.x;
  if (t < total) hg[t] *= 1.0f / (float)cnt[t >> 8];
}

extern "C" void kernel_launch(void* const* d_in, const int* in_sizes, int n_in,
                              void* d_out, int out_size, void* d_ws, size_t ws_size,
                              hipStream_t stream) {
  const float* feat = (const float*)d_in[0];
  const int* esrc = (const int*)d_in[1];
  const int* edst = (const int*)d_in[2];
  const int* gid = (const int*)d_in[3];
  const float* Ws0 = (const float*)d_in[4];
  const float* Wn0 = (const float*)d_in[5];
  const float* b0 = (const float*)d_in[6];
  const float* g0 = (const float*)d_in[7];
  const float* be0 = (const float*)d_in[8];
  const float* Ws1 = (const float*)d_in[9];
  const float* Wn1 = (const float*)d_in[10];
  const float* b1 = (const float*)d_in[11];
  const float* g1 = (const float*)d_in[12];
  const float* be1 = (const float*)d_in[13];
  const float* Ws2 = (const float*)d_in[14];
  const float* Wn2 = (const float*)d_in[15];
  const float* b2 = (const float*)d_in[16];
  const float* g2 = (const float*)d_in[17];
  const float* be2 = (const float*)d_in[18];

  const int E = in_sizes[1];
  const int n = in_sizes[3];
  const int DIN0 = in_sizes[0] / n;                 // 128
  const int Gn = (out_size - n * DOUT) / DOUT;      // 16
  const int nb = (n + 255) / 256;                   // scan blocks

  // workspace layout
  char* ws = (char*)d_ws;
  size_t off = 0;
  auto alloc = [&](size_t bytes) -> void* {
    void* p = ws + off;
    off += (bytes + 255) & ~(size_t)255;
    return p;
  };
  int* deg_cnt = (int*)alloc((size_t)n * 4);
  float* dinv = (float*)alloc((size_t)n * 4);
  int* gcnt = (int*)alloc((size_t)Gn * 4);
  int* row_ptr = (int*)alloc((size_t)(n + 1) * 4);
  int* cursor = (int*)alloc((size_t)n * 4);
  int* part = (int*)alloc((size_t)nb * 4);
  int* col = (int*)alloc((size_t)E * 4);
  float* bufA = (float*)alloc((size_t)n * DOUT * 4);
  float* bufB = (float*)alloc((size_t)n * DOUT * 4);

  float* out_h = (float*)d_out;
  float* out_hg = out_h + (size_t)n * DOUT;

  hipMemsetAsync(deg_cnt, 0, (size_t)n * 4, stream);
  hipMemsetAsync(gcnt, 0, (size_t)Gn * 4, stream);
  hipMemsetAsync(out_hg, 0, (size_t)Gn * DOUT * 4, stream);

  k_deg_count<<<(E + 255) / 256, 256, 0, stream>>>(edst, deg_cnt, E);
  k_deg_inv<<<(n + 255) / 256, 256, 0, stream>>>(deg_cnt, dinv, n);
  k_gcnt<<<(n + 255) / 256, 256, 0, stream>>>(gid, gcnt, n);

  // CSR build
  k_scan1<<<nb, 256, 0, stream>>>(deg_cnt, part, n);
  k_scan2<<<1, 256, 0, stream>>>(part, nb);
  k_scan3<<<nb, 256, 0, stream>>>(deg_cnt, part, row_ptr, cursor, n);
  k_fill<<<(E + 255) / 256, 256, 0, stream>>>(esrc, edst, cursor, col, E);

  dim3 gemm_grid((n + 63) / 64, DOUT / 64);
  int gather_grid = (n + 3) / 4;

  // ---- layer 0: h = feat (DIN0=128), agg->bufA, out->bufB ----
  k_gather<128><<<gather_grid, 256, 0, stream>>>(feat, row_ptr, col, dinv,
                                                 bufA, n);
  k_sage_gemm<128><<<gemm_grid, 256, 0, stream>>>(feat, bufA, Ws0, Wn0, b0,
                                                  bufB, n);
  k_ln_elu<<<(n + 3) / 4, 256, 0, stream>>>(bufB, g0, be0, n);

  // ---- layer 1: h = bufB, agg->bufA, out->out_h ----
  k_gather<256><<<gather_grid, 256, 0, stream>>>(bufB, row_ptr, col, dinv,
                                                 bufA, n);
  k_sage_gemm<256><<<gemm_grid, 256, 0, stream>>>(bufB, bufA, Ws1, Wn1, b1,
                                                  out_h, n);
  k_ln_elu<<<(n + 3) / 4, 256, 0, stream>>>(out_h, g1, be1, n);

  // ---- layer 2: h = out_h, agg->bufA, out->bufB ----
  k_gather<256><<<gather_grid, 256, 0, stream>>>(out_h, row_ptr, col, dinv,
                                                 bufA, n);
  k_sage_gemm<256><<<gemm_grid, 256, 0, stream>>>(out_h, bufA, Ws2, Wn2, b2,
                                                  bufB, n);
  k_ln_elu<<<(n + 3) / 4, 256, 0, stream>>>(bufB, g2, be2, n);

  // ---- readout from bufB; copy final h to d_out ----
  k_readout<<<(n + 63) / 64, 256, 0, stream>>>(bufB, gid, out_hg, n);
  k_hg_scale<<<(Gn * DOUT + 255) / 256, 256, 0, stream>>>(out_hg, gcnt,
                                                          Gn * DOUT);
  hipMemcpyAsync(out_h, bufB, (size_t)n * DOUT * 4, hipMemcpyDeviceToDevice,
                 stream);
}

// Round 3
// 463.840 us; speedup vs baseline: 14.3605x; 3.2774x over previous
//
#include <hip/hip_runtime.h>
#include <hip/hip_bf16.h>

constexpr int DOUT = 256;

typedef __bf16 bf16x8 __attribute__((ext_vector_type(8)));
typedef float f32x4 __attribute__((ext_vector_type(4)));

__device__ inline float bf2f(ushort u) {
  return __uint_as_float((unsigned)u << 16);
}
__device__ inline ushort f2bf(float f) {
  unsigned b = __float_as_uint(f);
  return (ushort)((b + 0x7FFF + ((b >> 16) & 1)) >> 16);  // RNE
}

// ---------------- degree / counts ----------------
__global__ __launch_bounds__(256) void k_deg_count(const int* __restrict__ dst,
                                                   int* __restrict__ cnt, int E) {
  int t = blockIdx.x * blockDim.x + threadIdx.x;
  if (t < E) atomicAdd(&cnt[dst[t]], 1);
}

__global__ __launch_bounds__(256) void k_deg_inv(const int* __restrict__ cnt,
                                                 float* __restrict__ dinv, int n) {
  int t = blockIdx.x * blockDim.x + threadIdx.x;
  if (t < n) dinv[t] = 1.0f / (float)cnt[t];
}

// LDS-histogram graph-count (16 bins; global atomics only per block)
__global__ __launch_bounds__(256) void k_gcnt(const int* __restrict__ gid,
                                              int* __restrict__ cnt, int n, int G) {
  __shared__ int h[256];
  int t = threadIdx.x;
  if (t < G) h[t] = 0;
  __syncthreads();
  int i = blockIdx.x * 256 + t;
  if (i < n) atomicAdd(&h[gid[i]], 1);
  __syncthreads();
  if (t < G && h[t]) atomicAdd(&cnt[t], h[t]);
}

// ---------------- CSR build: 3-kernel exclusive scan + fill ----------------
__global__ __launch_bounds__(256) void k_scan1(const int* __restrict__ deg,
                                               int* __restrict__ part, int n) {
  int i = blockIdx.x * 256 + threadIdx.x;
  int v = (i < n) ? deg[i] : 0;
#pragma unroll
  for (int o = 32; o > 0; o >>= 1) v += __shfl_xor(v, o);
  __shared__ int s[4];
  int wave = threadIdx.x >> 6, lane = threadIdx.x & 63;
  if (lane == 0) s[wave] = v;
  __syncthreads();
  if (threadIdx.x == 0) part[blockIdx.x] = s[0] + s[1] + s[2] + s[3];
}

__global__ __launch_bounds__(256) void k_scan2(int* __restrict__ part, int nb) {
  __shared__ int s[256];
  int t = threadIdx.x;
  int v = (t < nb) ? part[t] : 0;
  s[t] = v;
  __syncthreads();
  for (int o = 1; o < 256; o <<= 1) {
    int u = (t >= o) ? s[t - o] : 0;
    __syncthreads();
    s[t] += u;
    __syncthreads();
  }
  int excl = (t == 0) ? 0 : s[t - 1];
  if (t < nb) part[t] = excl;
}

__global__ __launch_bounds__(256) void k_scan3(const int* __restrict__ deg,
                                               const int* __restrict__ part,
                                               int* __restrict__ rp,
                                               int* __restrict__ cur, int n) {
  __shared__ int s[256];
  int t = threadIdx.x;
  int i = blockIdx.x * 256 + t;
  int v = (i < n) ? deg[i] : 0;
  s[t] = v;
  __syncthreads();
  for (int o = 1; o < 256; o <<= 1) {
    int u = (t >= o) ? s[t - o] : 0;
    __syncthreads();
    s[t] += u;
    __syncthreads();
  }
  int incl = s[t];
  int excl = incl - v;
  int base = part[blockIdx.x];
  if (i < n) {
    rp[i] = base + excl;
    cur[i] = base + excl;
  }
  if (i == n - 1) rp[n] = base + incl;
}

__global__ __launch_bounds__(256) void k_fill(const int* __restrict__ src,
                                              const int* __restrict__ dst,
                                              int* __restrict__ cur,
                                              int* __restrict__ col, int E) {
  int e = blockIdx.x * 256 + threadIdx.x;
  if (e < E) {
    int p = atomicAdd(&cur[dst[e]], 1);
    col[p] = src[e];
  }
}

// ---------------- cast fp32 -> bf16 ----------------
__global__ __launch_bounds__(256) void k_cast_bf16(const float* __restrict__ in,
                                                   ushort* __restrict__ out,
                                                   long long total4) {
  long long t = (long long)blockIdx.x * 256 + threadIdx.x;
  if (t >= total4) return;
  float4 v = *(const float4*)(in + t * 4);
  ushort4 o;
  o.x = f2bf(v.x); o.y = f2bf(v.y); o.z = f2bf(v.z); o.w = f2bf(v.w);
  *(ushort4*)(out + t * 4) = o;
}

// ---------------- weight prep: Wt[n][k] bf16, K = 2*DIN ----------------
__global__ __launch_bounds__(256) void k_prep_w(const float* __restrict__ Ws,
                                                const float* __restrict__ Wn,
                                                ushort* __restrict__ Wt, int DIN) {
  int t = blockIdx.x * 256 + threadIdx.x;
  int K = 2 * DIN;
  int nn = t & 255;
  int k = t >> 8;
  if (k >= K) return;
  const float* W = (k < DIN) ? (Ws + (size_t)k * 256) : (Wn + (size_t)(k - DIN) * 256);
  Wt[(size_t)nn * K + k] = f2bf(W[nn]);
}

// ---------------- CSR gather (bf16 in, bf16 out): agg[i] = dinv[i]*sum h[col[j]]
template <int DIN>
__global__ __launch_bounds__(256) void k_gather(const ushort* __restrict__ h,
                                                const int* __restrict__ rp,
                                                const int* __restrict__ col,
                                                const float* __restrict__ dinv,
                                                ushort* __restrict__ agg, int n) {
  int wave = threadIdx.x >> 6, lane = threadIdx.x & 63;
  int node = blockIdx.x * 4 + wave;
  if (node >= n) return;
  int beg = rp[node], end = rp[node + 1];
  float s = dinv[node];
  if constexpr (DIN == 256) {
    const ushort* base = h + lane * 4;
    float a0 = 0.f, a1 = 0.f, a2 = 0.f, a3 = 0.f;
    for (int j = beg; j < end; ++j) {
      ushort4 v = *(const ushort4*)(base + (size_t)col[j] * DIN);
      a0 += bf2f(v.x); a1 += bf2f(v.y); a2 += bf2f(v.z); a3 += bf2f(v.w);
    }
    ushort4 o;
    o.x = f2bf(a0 * s); o.y = f2bf(a1 * s); o.z = f2bf(a2 * s); o.w = f2bf(a3 * s);
    *(ushort4*)(agg + (size_t)node * DIN + lane * 4) = o;
  } else {  // DIN == 128
    const ushort* base = h + lane * 2;
    float a0 = 0.f, a1 = 0.f;
    for (int j = beg; j < end; ++j) {
      ushort2 v = *(const ushort2*)(base + (size_t)col[j] * DIN);
      a0 += bf2f(v.x); a1 += bf2f(v.y);
    }
    ushort2 o;
    o.x = f2bf(a0 * s); o.y = f2bf(a1 * s);
    *(ushort2*)(agg + (size_t)node * DIN + lane * 2) = o;
  }
}

// ---------------- bf16 MFMA dual GEMM: out = [A0|A1] @ Wt^T + bias ----------
// A0,A1: [n][DIN] bf16 (k-contiguous). Wt: [256][K] bf16 (k-contiguous).
// Block 128x128, 4 waves (2x2), wave tile 64x64 = 4x4 frags of 16x16, K-step 32.
template <int DIN>
__global__ __launch_bounds__(256) void k_gemm(const ushort* __restrict__ A0,
                                              const ushort* __restrict__ A1,
                                              const ushort* __restrict__ Wt,
                                              const float* __restrict__ bias,
                                              float* __restrict__ out, int n) {
  constexpr int K = 2 * DIN;
  __shared__ ushort As[128 * 32];
  __shared__ ushort Bs[128 * 32];
  const int tid = threadIdx.x;
  const int lane = tid & 63, wid = tid >> 6;
  const int wr = wid >> 1, wc = wid & 1;
  const int m0 = blockIdx.x * 128, n0 = blockIdx.y * 128;
  const int fr = lane & 15, kg = lane >> 4;
  const int s_row = tid >> 2, s_c = tid & 3;  // staging: 64 rows x 4 chunks/round

  f32x4 acc[4][4] = {};

  for (int k0 = 0; k0 < K; k0 += 32) {
    const ushort* Asrc = (k0 < DIN) ? A0 : A1;
    const int ak = (k0 < DIN) ? k0 : (k0 - DIN);
#pragma unroll
    for (int r = 0; r < 2; ++r) {
      int row = s_row + r * 64;
      int grow = m0 + row;
      int4 v = make_int4(0, 0, 0, 0);
      if (grow < n) v = *(const int4*)(Asrc + (size_t)grow * DIN + ak + s_c * 8);
      *(int4*)&As[row * 32 + ((s_c ^ (row & 3)) * 8)] = v;
      int4 w = *(const int4*)(Wt + (size_t)(n0 + row) * K + k0 + s_c * 8);
      *(int4*)&Bs[row * 32 + ((s_c ^ (row & 3)) * 8)] = w;
    }
    __syncthreads();
    bf16x8 af[4], bb[4];
#pragma unroll
    for (int mi = 0; mi < 4; ++mi) {
      int row = wr * 64 + mi * 16 + fr;
      af[mi] = *(const bf16x8*)&As[row * 32 + ((kg ^ (row & 3)) * 8)];
    }
#pragma unroll
    for (int ni = 0; ni < 4; ++ni) {
      int row = wc * 64 + ni * 16 + fr;
      bb[ni] = *(const bf16x8*)&Bs[row * 32 + ((kg ^ (row & 3)) * 8)];
    }
#pragma unroll
    for (int mi = 0; mi < 4; ++mi)
#pragma unroll
      for (int ni = 0; ni < 4; ++ni)
        acc[mi][ni] = __builtin_amdgcn_mfma_f32_16x16x32_bf16(af[mi], bb[ni],
                                                              acc[mi][ni], 0, 0, 0);
    __syncthreads();
  }
  // C/D: col = lane&15, row = (lane>>4)*4 + reg  [m89-verified]
#pragma unroll
  for (int mi = 0; mi < 4; ++mi) {
    int r0 = m0 + wr * 64 + mi * 16 + kg * 4;
#pragma unroll
    for (int j = 0; j < 4; ++j) {
      int r = r0 + j;
      if (r < n) {
#pragma unroll
        for (int ni = 0; ni < 4; ++ni) {
          int c = n0 + wc * 64 + ni * 16 + fr;
          out[(size_t)r * DOUT + c] = acc[mi][ni][j] + bias[c];
        }
      }
    }
  }
}

// ---------------- LayerNorm + ELU; bf16 or fp32 out ----------------
template <bool BF16OUT>
__global__ __launch_bounds__(256) void k_ln_elu(const float* __restrict__ x,
                                                const float* __restrict__ g,
                                                const float* __restrict__ be,
                                                ushort* __restrict__ outB,
                                                float* __restrict__ outF, int n) {
  int wave = threadIdx.x >> 6;
  int lane = threadIdx.x & 63;
  int row = blockIdx.x * 4 + wave;
  if (row >= n) return;
  const float* p = x + (size_t)row * DOUT + lane * 4;
  float4 v = *(const float4*)p;
  float s = v.x + v.y + v.z + v.w;
#pragma unroll
  for (int o = 32; o > 0; o >>= 1) s += __shfl_xor(s, o);
  float mean = s * (1.0f / 256.0f);
  float dx = v.x - mean, dy = v.y - mean, dz = v.z - mean, dw = v.w - mean;
  float q = dx * dx + dy * dy + dz * dz + dw * dw;
#pragma unroll
  for (int o = 32; o > 0; o >>= 1) q += __shfl_xor(q, o);
  float rstd = rsqrtf(q * (1.0f / 256.0f) + 1e-5f);
  int c = lane * 4;
  float4 gg = *(const float4*)(g + c);
  float4 bb = *(const float4*)(be + c);
  float o0 = dx * rstd * gg.x + bb.x;
  float o1 = dy * rstd * gg.y + bb.y;
  float o2 = dz * rstd * gg.z + bb.z;
  float o3 = dw * rstd * gg.w + bb.w;
  o0 = o0 > 0.f ? o0 : expm1f(o0);
  o1 = o1 > 0.f ? o1 : expm1f(o1);
  o2 = o2 > 0.f ? o2 : expm1f(o2);
  o3 = o3 > 0.f ? o3 : expm1f(o3);
  if constexpr (BF16OUT) {
    ushort4 o;
    o.x = f2bf(o0); o.y = f2bf(o1); o.z = f2bf(o2); o.w = f2bf(o3);
    *(ushort4*)(outB + (size_t)row * DOUT + c) = o;
  } else {
    *(float4*)(outF + (size_t)row * DOUT + c) = make_float4(o0, o1, o2, o3);
  }
}

// ---------------- per-graph mean readout ----------------
__global__ __launch_bounds__(256) void k_readout(const float* __restrict__ h,
                                                 const int* __restrict__ gid,
                                                 float* __restrict__ hg, int n) {
  int start = blockIdx.x * 64;
  int end = min(start + 64, n);
  int c = threadIdx.x;
  float acc = 0.f;
  int cur = gid[start];
  for (int i = start; i < end; ++i) {
    int g = gid[i];
    if (g != cur) {
      atomicAdd(&hg[(size_t)cur * DOUT + c], acc);
      acc = 0.f;
      cur = g;
    }
    acc += h[(size_t)i * DOUT + c];
  }
  atomicAdd(&hg[(size_t)cur * DOUT + c], acc);
}

__global__ __launch_bounds__(256) void k_hg_scale(float* __restrict__ hg,
                                                  const int* __restrict__ cnt,
                                                  int total) {
  int t = blockIdx.x * blockDim.x + threadIdx.x;
  if (t < total) hg[t] *= 1.0f / (float)cnt[t >> 8];
}

extern "C" void kernel_launch(void* const* d_in, const int* in_sizes, int n_in,
                              void* d_out, int out_size, void* d_ws, size_t ws_size,
                              hipStream_t stream) {
  const float* feat = (const float*)d_in[0];
  const int* esrc = (const int*)d_in[1];
  const int* edst = (const int*)d_in[2];
  const int* gid = (const int*)d_in[3];
  const float* Ws0 = (const float*)d_in[4];
  const float* Wn0 = (const float*)d_in[5];
  const float* b0 = (const float*)d_in[6];
  const float* g0 = (const float*)d_in[7];
  const float* be0 = (const float*)d_in[8];
  const float* Ws1 = (const float*)d_in[9];
  const float* Wn1 = (const float*)d_in[10];
  const float* b1 = (const float*)d_in[11];
  const float* g1 = (const float*)d_in[12];
  const float* be1 = (const float*)d_in[13];
  const float* Ws2 = (const float*)d_in[14];
  const float* Wn2 = (const float*)d_in[15];
  const float* b2 = (const float*)d_in[16];
  const float* g2 = (const float*)d_in[17];
  const float* be2 = (const float*)d_in[18];

  const int E = in_sizes[1];
  const int n = in_sizes[3];
  const int DIN0 = in_sizes[0] / n;             // 128
  const int Gn = (out_size - n * DOUT) / DOUT;  // 16
  const int nb = (n + 255) / 256;

  char* ws = (char*)d_ws;
  size_t off = 0;
  auto alloc = [&](size_t bytes) -> void* {
    void* p = ws + off;
    off += (bytes + 255) & ~(size_t)255;
    return p;
  };
  int* deg_cnt = (int*)alloc((size_t)n * 4);
  float* dinv = (float*)alloc((size_t)n * 4);
  int* gcnt = (int*)alloc((size_t)Gn * 4);
  int* row_ptr = (int*)alloc((size_t)(n + 1) * 4);
  int* cursor = (int*)alloc((size_t)n * 4);
  int* part = (int*)alloc((size_t)nb * 4);
  int* col = (int*)alloc((size_t)E * 4);
  ushort* feat_bf = (ushort*)alloc((size_t)n * DIN0 * 2);
  ushort* h_bf = (ushort*)alloc((size_t)n * DOUT * 2);
  ushort* agg_bf = (ushort*)alloc((size_t)n * DOUT * 2);
  float* bufC = (float*)alloc((size_t)n * DOUT * 4);
  ushort* Wt0 = (ushort*)alloc((size_t)256 * 2 * DIN0 * 2);
  ushort* Wt1 = (ushort*)alloc((size_t)256 * 2 * DOUT * 2);
  ushort* Wt2 = (ushort*)alloc((size_t)256 * 2 * DOUT * 2);

  float* out_h = (float*)d_out;
  float* out_hg = out_h + (size_t)n * DOUT;

  hipMemsetAsync(deg_cnt, 0, (size_t)n * 4, stream);
  hipMemsetAsync(gcnt, 0, (size_t)Gn * 4, stream);
  hipMemsetAsync(out_hg, 0, (size_t)Gn * DOUT * 4, stream);

  k_deg_count<<<(E + 255) / 256, 256, 0, stream>>>(edst, deg_cnt, E);
  k_deg_inv<<<(n + 255) / 256, 256, 0, stream>>>(deg_cnt, dinv, n);
  k_gcnt<<<nb, 256, 0, stream>>>(gid, gcnt, n, Gn);

  // CSR build
  k_scan1<<<nb, 256, 0, stream>>>(deg_cnt, part, n);
  k_scan2<<<1, 256, 0, stream>>>(part, nb);
  k_scan3<<<nb, 256, 0, stream>>>(deg_cnt, part, row_ptr, cursor, n);
  k_fill<<<(E + 255) / 256, 256, 0, stream>>>(esrc, edst, cursor, col, E);

  // prep: cast features, transpose weights to bf16 [n][k]
  k_cast_bf16<<<(int)(((long long)n * DIN0 / 4 + 255) / 256), 256, 0, stream>>>(
      feat, feat_bf, (long long)n * DIN0 / 4);
  k_prep_w<<<2 * DIN0, 256, 0, stream>>>(Ws0, Wn0, Wt0, DIN0);
  k_prep_w<<<2 * DOUT, 256, 0, stream>>>(Ws1, Wn1, Wt1, DOUT);
  k_prep_w<<<2 * DOUT, 256, 0, stream>>>(Ws2, Wn2, Wt2, DOUT);

  dim3 gemm_grid((n + 127) / 128, DOUT / 128);
  int row_grid = (n + 3) / 4;

  // ---- layer 0 ----
  k_gather<128><<<row_grid, 256, 0, stream>>>(feat_bf, row_ptr, col, dinv,
                                              agg_bf, n);
  k_gemm<128><<<gemm_grid, 256, 0, stream>>>(feat_bf, agg_bf, Wt0, b0, bufC, n);
  k_ln_elu<true><<<row_grid, 256, 0, stream>>>(bufC, g0, be0, h_bf, nullptr, n);

  // ---- layer 1 ----
  k_gather<256><<<row_grid, 256, 0, stream>>>(h_bf, row_ptr, col, dinv,
                                              agg_bf, n);
  k_gemm<256><<<gemm_grid, 256, 0, stream>>>(h_bf, agg_bf, Wt1, b1, bufC, n);
  k_ln_elu<true><<<row_grid, 256, 0, stream>>>(bufC, g1, be1, h_bf, nullptr, n);

  // ---- layer 2: gemm -> d_out, LN in place (fp32) ----
  k_gather<256><<<row_grid, 256, 0, stream>>>(h_bf, row_ptr, col, dinv,
                                              agg_bf, n);
  k_gemm<256><<<gemm_grid, 256, 0, stream>>>(h_bf, agg_bf, Wt2, b2, out_h, n);
  k_ln_elu<false><<<row_grid, 256, 0, stream>>>(out_h, g2, be2, nullptr, out_h, n);

  // ---- readout ----
  k_readout<<<(n + 63) / 64, 256, 0, stream>>>(out_h, gid, out_hg, n);
  k_hg_scale<<<(Gn * DOUT + 255) / 256, 256, 0, stream>>>(out_hg, gcnt,
                                                          Gn * DOUT);
}

// Round 4
// 352.663 us; speedup vs baseline: 18.8876x; 1.3152x over previous
//
#include <hip/hip_runtime.h>
#include <hip/hip_bf16.h>

constexpr int DOUT = 256;

typedef __bf16 bf16x8 __attribute__((ext_vector_type(8)));
typedef float f32x4 __attribute__((ext_vector_type(4)));

__device__ inline float bf2f(ushort u) {
  return __uint_as_float((unsigned)u << 16);
}
__device__ inline ushort f2bf(float f) {
  unsigned b = __float_as_uint(f);
  return (ushort)((b + 0x7FFF + ((b >> 16) & 1)) >> 16);  // RNE
}

// bijective XCD chunk swizzle (m204): contiguous work chunks per XCD
__device__ inline int xcd_swizzle(int bid, int nwg) {
  int q = nwg >> 3, r = nwg & 7;
  int xcd = bid & 7, idx = bid >> 3;
  return (xcd < r ? xcd * (q + 1) : r * (q + 1) + (xcd - r) * q) + idx;
}

// ---------------- degree / counts ----------------
__global__ __launch_bounds__(256) void k_deg_count(const int* __restrict__ dst,
                                                   int* __restrict__ cnt, int E) {
  int t = blockIdx.x * blockDim.x + threadIdx.x;
  if (t < E) atomicAdd(&cnt[dst[t]], 1);
}

__global__ __launch_bounds__(256) void k_deg_inv(const int* __restrict__ cnt,
                                                 float* __restrict__ dinv, int n) {
  int t = blockIdx.x * blockDim.x + threadIdx.x;
  if (t < n) dinv[t] = 1.0f / (float)cnt[t];
}

__global__ __launch_bounds__(256) void k_gcnt(const int* __restrict__ gid,
                                              int* __restrict__ cnt, int n, int G) {
  __shared__ int h[256];
  int t = threadIdx.x;
  if (t < G) h[t] = 0;
  __syncthreads();
  int i = blockIdx.x * 256 + t;
  if (i < n) atomicAdd(&h[gid[i]], 1);
  __syncthreads();
  if (t < G && h[t]) atomicAdd(&cnt[t], h[t]);
}

// ---------------- CSR build ----------------
__global__ __launch_bounds__(256) void k_scan1(const int* __restrict__ deg,
                                               int* __restrict__ part, int n) {
  int i = blockIdx.x * 256 + threadIdx.x;
  int v = (i < n) ? deg[i] : 0;
#pragma unroll
  for (int o = 32; o > 0; o >>= 1) v += __shfl_xor(v, o);
  __shared__ int s[4];
  int wave = threadIdx.x >> 6, lane = threadIdx.x & 63;
  if (lane == 0) s[wave] = v;
  __syncthreads();
  if (threadIdx.x == 0) part[blockIdx.x] = s[0] + s[1] + s[2] + s[3];
}

__global__ __launch_bounds__(256) void k_scan2(int* __restrict__ part, int nb) {
  __shared__ int s[256];
  int t = threadIdx.x;
  int v = (t < nb) ? part[t] : 0;
  s[t] = v;
  __syncthreads();
  for (int o = 1; o < 256; o <<= 1) {
    int u = (t >= o) ? s[t - o] : 0;
    __syncthreads();
    s[t] += u;
    __syncthreads();
  }
  int excl = (t == 0) ? 0 : s[t - 1];
  if (t < nb) part[t] = excl;
}

__global__ __launch_bounds__(256) void k_scan3(const int* __restrict__ deg,
                                               const int* __restrict__ part,
                                               int* __restrict__ rp,
                                               int* __restrict__ cur, int n) {
  __shared__ int s[256];
  int t = threadIdx.x;
  int i = blockIdx.x * 256 + t;
  int v = (i < n) ? deg[i] : 0;
  s[t] = v;
  __syncthreads();
  for (int o = 1; o < 256; o <<= 1) {
    int u = (t >= o) ? s[t - o] : 0;
    __syncthreads();
    s[t] += u;
    __syncthreads();
  }
  int incl = s[t];
  int excl = incl - v;
  int base = part[blockIdx.x];
  if (i < n) {
    rp[i] = base + excl;
    cur[i] = base + excl;
  }
  if (i == n - 1) rp[n] = base + incl;
}

__global__ __launch_bounds__(256) void k_fill(const int* __restrict__ src,
                                              const int* __restrict__ dst,
                                              int* __restrict__ cur,
                                              int* __restrict__ col, int E) {
  int e = blockIdx.x * 256 + threadIdx.x;
  if (e < E) {
    int p = atomicAdd(&cur[dst[e]], 1);
    col[p] = src[e];
  }
}

// ---------------- cast fp32 -> bf16 ----------------
__global__ __launch_bounds__(256) void k_cast_bf16(const float* __restrict__ in,
                                                   ushort* __restrict__ out,
                                                   long long total4) {
  long long t = (long long)blockIdx.x * 256 + threadIdx.x;
  if (t >= total4) return;
  float4 v = *(const float4*)(in + t * 4);
  ushort4 o;
  o.x = f2bf(v.x); o.y = f2bf(v.y); o.z = f2bf(v.z); o.w = f2bf(v.w);
  *(ushort4*)(out + t * 4) = o;
}

// ---------------- weight prep: Wt[n][k] bf16, K = 2*DIN ----------------
__global__ __launch_bounds__(256) void k_prep_w(const float* __restrict__ Ws,
                                                const float* __restrict__ Wn,
                                                ushort* __restrict__ Wt, int DIN) {
  int t = blockIdx.x * 256 + threadIdx.x;
  int K = 2 * DIN;
  int nn = t & 255;
  int k = t >> 8;
  if (k >= K) return;
  const float* W = (k < DIN) ? (Ws + (size_t)k * 256) : (Wn + (size_t)(k - DIN) * 256);
  Wt[(size_t)nn * K + k] = f2bf(W[nn]);
}

// ---------------- CSR gather (bf16), XCD-swizzled ----------------
template <int DIN>
__global__ __launch_bounds__(256) void k_gather(const ushort* __restrict__ h,
                                                const int* __restrict__ rp,
                                                const int* __restrict__ col,
                                                const float* __restrict__ dinv,
                                                ushort* __restrict__ agg, int n) {
  int wg = xcd_swizzle(blockIdx.x, gridDim.x);
  int wave = threadIdx.x >> 6, lane = threadIdx.x & 63;
  int node = wg * 4 + wave;
  if (node >= n) return;
  int beg = rp[node], end = rp[node + 1];
  float s = dinv[node];
  if constexpr (DIN == 256) {
    const ushort* base = h + lane * 4;
    float a0 = 0.f, a1 = 0.f, a2 = 0.f, a3 = 0.f;
    int j = beg;
    for (; j + 1 < end; j += 2) {
      int c0 = col[j], c1 = col[j + 1];
      ushort4 v0 = *(const ushort4*)(base + (size_t)c0 * DIN);
      ushort4 v1 = *(const ushort4*)(base + (size_t)c1 * DIN);
      a0 += bf2f(v0.x) + bf2f(v1.x);
      a1 += bf2f(v0.y) + bf2f(v1.y);
      a2 += bf2f(v0.z) + bf2f(v1.z);
      a3 += bf2f(v0.w) + bf2f(v1.w);
    }
    if (j < end) {
      ushort4 v = *(const ushort4*)(base + (size_t)col[j] * DIN);
      a0 += bf2f(v.x); a1 += bf2f(v.y); a2 += bf2f(v.z); a3 += bf2f(v.w);
    }
    ushort4 o;
    o.x = f2bf(a0 * s); o.y = f2bf(a1 * s); o.z = f2bf(a2 * s); o.w = f2bf(a3 * s);
    *(ushort4*)(agg + (size_t)node * DIN + lane * 4) = o;
  } else {  // DIN == 128
    const ushort* base = h + lane * 2;
    float a0 = 0.f, a1 = 0.f;
    int j = beg;
    for (; j + 1 < end; j += 2) {
      int c0 = col[j], c1 = col[j + 1];
      ushort2 v0 = *(const ushort2*)(base + (size_t)c0 * DIN);
      ushort2 v1 = *(const ushort2*)(base + (size_t)c1 * DIN);
      a0 += bf2f(v0.x) + bf2f(v1.x);
      a1 += bf2f(v0.y) + bf2f(v1.y);
    }
    if (j < end) {
      ushort2 v = *(const ushort2*)(base + (size_t)col[j] * DIN);
      a0 += bf2f(v.x); a1 += bf2f(v.y);
    }
    ushort2 o;
    o.x = f2bf(a0 * s); o.y = f2bf(a1 * s);
    *(ushort2*)(agg + (size_t)node * DIN + lane * 2) = o;
  }
}

// ---------------- fused GEMM + bias + LayerNorm + ELU ----------------
// Block: 128 rows x all 256 cols, 512 threads = 8 waves (2 row x 4 col).
// out = LN(A@Wt^T + bias) with A = [A0|A1]; writes bf16 (h) or fp32 (d_out).
template <int DIN, bool BF16OUT>
__global__ __launch_bounds__(512) void k_gemm_ln(
    const ushort* __restrict__ A0, const ushort* __restrict__ A1,
    const ushort* __restrict__ Wt, const float* __restrict__ bias,
    const float* __restrict__ g, const float* __restrict__ be,
    ushort* __restrict__ outB, float* __restrict__ outF, int n) {
  constexpr int K = 2 * DIN;
  __shared__ ushort As[128 * 32];
  __shared__ ushort Bs[256 * 32];
  __shared__ float redS[4][128];
  __shared__ float redQ[4][128];
  const int tid = threadIdx.x;
  const int lane = tid & 63, wid = tid >> 6;
  const int wr = wid >> 2, wc = wid & 3;  // wave tile: rows wr*64, cols wc*64
  const int m0 = blockIdx.x * 128;
  const int fr = lane & 15, kg = lane >> 4;
  const int s_row = tid >> 2, s_c = tid & 3;

  f32x4 acc[4][4] = {};

  for (int k0 = 0; k0 < K; k0 += 32) {
    const ushort* Asrc = (k0 < DIN) ? A0 : A1;
    const int ak = (k0 < DIN) ? k0 : (k0 - DIN);
    {
      int grow = m0 + s_row;
      int4 v = make_int4(0, 0, 0, 0);
      if (grow < n) v = *(const int4*)(Asrc + (size_t)grow * DIN + ak + s_c * 8);
      *(int4*)&As[s_row * 32 + ((s_c ^ (s_row & 3)) * 8)] = v;
      int4 w0 = *(const int4*)(Wt + (size_t)s_row * K + k0 + s_c * 8);
      *(int4*)&Bs[s_row * 32 + ((s_c ^ (s_row & 3)) * 8)] = w0;
      int r2 = s_row + 128;
      int4 w1 = *(const int4*)(Wt + (size_t)r2 * K + k0 + s_c * 8);
      *(int4*)&Bs[r2 * 32 + ((s_c ^ (r2 & 3)) * 8)] = w1;
    }
    __syncthreads();
    bf16x8 af[4], bb[4];
#pragma unroll
    for (int mi = 0; mi < 4; ++mi) {
      int row = wr * 64 + mi * 16 + fr;
      af[mi] = *(const bf16x8*)&As[row * 32 + ((kg ^ (row & 3)) * 8)];
    }
#pragma unroll
    for (int ni = 0; ni < 4; ++ni) {
      int row = wc * 64 + ni * 16 + fr;
      bb[ni] = *(const bf16x8*)&Bs[row * 32 + ((kg ^ (row & 3)) * 8)];
    }
#pragma unroll
    for (int mi = 0; mi < 4; ++mi)
#pragma unroll
      for (int ni = 0; ni < 4; ++ni)
        acc[mi][ni] = __builtin_amdgcn_mfma_f32_16x16x32_bf16(af[mi], bb[ni],
                                                              acc[mi][ni], 0, 0, 0);
    __syncthreads();
  }

  // ---- epilogue: bias, row stats, LN, ELU, store ----
  float bv[4], gv[4], ev[4];
#pragma unroll
  for (int ni = 0; ni < 4; ++ni) {
    int c = wc * 64 + ni * 16 + fr;
    bv[ni] = bias[c];
    gv[ni] = g[c];
    ev[ni] = be[c];
  }
#pragma unroll
  for (int mi = 0; mi < 4; ++mi)
#pragma unroll
    for (int ni = 0; ni < 4; ++ni)
#pragma unroll
      for (int j = 0; j < 4; ++j) acc[mi][ni][j] += bv[ni];

  // per-row partial sums over this wave's 64 cols
#pragma unroll
  for (int mi = 0; mi < 4; ++mi) {
#pragma unroll
    for (int j = 0; j < 4; ++j) {
      float s = 0.f, q = 0.f;
#pragma unroll
      for (int ni = 0; ni < 4; ++ni) {
        float a = acc[mi][ni][j];
        s += a;
        q += a * a;
      }
#pragma unroll
      for (int o = 1; o < 16; o <<= 1) {
        s += __shfl_xor(s, o);
        q += __shfl_xor(q, o);
      }
      if (fr == 0) {
        int lr = wr * 64 + mi * 16 + kg * 4 + j;
        redS[wc][lr] = s;
        redQ[wc][lr] = q;
      }
    }
  }
  __syncthreads();
#pragma unroll
  for (int mi = 0; mi < 4; ++mi) {
#pragma unroll
    for (int j = 0; j < 4; ++j) {
      int lr = wr * 64 + mi * 16 + kg * 4 + j;
      int r = m0 + lr;
      if (r >= n) continue;
      float tot = redS[0][lr] + redS[1][lr] + redS[2][lr] + redS[3][lr];
      float tq = redQ[0][lr] + redQ[1][lr] + redQ[2][lr] + redQ[3][lr];
      float mean = tot * (1.0f / 256.0f);
      float var = tq * (1.0f / 256.0f) - mean * mean;
      float rstd = rsqrtf(var + 1e-5f);
#pragma unroll
      for (int ni = 0; ni < 4; ++ni) {
        int c = wc * 64 + ni * 16 + fr;
        float val = (acc[mi][ni][j] - mean) * rstd * gv[ni] + ev[ni];
        val = val > 0.f ? val : expm1f(val);
        if constexpr (BF16OUT)
          outB[(size_t)r * DOUT + c] = f2bf(val);
        else
          outF[(size_t)r * DOUT + c] = val;
      }
    }
  }
}

// ---------------- per-graph mean readout ----------------
__global__ __launch_bounds__(256) void k_readout(const float* __restrict__ h,
                                                 const int* __restrict__ gid,
                                                 float* __restrict__ hg, int n) {
  int start = blockIdx.x * 64;
  int end = min(start + 64, n);
  int c = threadIdx.x;
  float acc = 0.f;
  int cur = gid[start];
  for (int i = start; i < end; ++i) {
    int g = gid[i];
    if (g != cur) {
      atomicAdd(&hg[(size_t)cur * DOUT + c], acc);
      acc = 0.f;
      cur = g;
    }
    acc += h[(size_t)i * DOUT + c];
  }
  atomicAdd(&hg[(size_t)cur * DOUT + c], acc);
}

__global__ __launch_bounds__(256) void k_hg_scale(float* __restrict__ hg,
                                                  const int* __restrict__ cnt,
                                                  int total) {
  int t = blockIdx.x * blockDim.x + threadIdx.x;
  if (t < total) hg[t] *= 1.0f / (float)cnt[t >> 8];
}

extern "C" void kernel_launch(void* const* d_in, const int* in_sizes, int n_in,
                              void* d_out, int out_size, void* d_ws, size_t ws_size,
                              hipStream_t stream) {
  const float* feat = (const float*)d_in[0];
  const int* esrc = (const int*)d_in[1];
  const int* edst = (const int*)d_in[2];
  const int* gid = (const int*)d_in[3];
  const float* Ws0 = (const float*)d_in[4];
  const float* Wn0 = (const float*)d_in[5];
  const float* b0 = (const float*)d_in[6];
  const float* g0 = (const float*)d_in[7];
  const float* be0 = (const float*)d_in[8];
  const float* Ws1 = (const float*)d_in[9];
  const float* Wn1 = (const float*)d_in[10];
  const float* b1 = (const float*)d_in[11];
  const float* g1 = (const float*)d_in[12];
  const float* be1 = (const float*)d_in[13];
  const float* Ws2 = (const float*)d_in[14];
  const float* Wn2 = (const float*)d_in[15];
  const float* b2 = (const float*)d_in[16];
  const float* g2 = (const float*)d_in[17];
  const float* be2 = (const float*)d_in[18];

  const int E = in_sizes[1];
  const int n = in_sizes[3];
  const int DIN0 = in_sizes[0] / n;             // 128
  const int Gn = (out_size - n * DOUT) / DOUT;  // 16
  const int nb = (n + 255) / 256;

  char* ws = (char*)d_ws;
  size_t off = 0;
  auto alloc = [&](size_t bytes) -> void* {
    void* p = ws + off;
    off += (bytes + 255) & ~(size_t)255;
    return p;
  };
  int* deg_cnt = (int*)alloc((size_t)n * 4);
  float* dinv = (float*)alloc((size_t)n * 4);
  int* gcnt = (int*)alloc((size_t)Gn * 4);
  int* row_ptr = (int*)alloc((size_t)(n + 1) * 4);
  int* cursor = (int*)alloc((size_t)n * 4);
  int* part = (int*)alloc((size_t)nb * 4);
  int* col = (int*)alloc((size_t)E * 4);
  ushort* feat_bf = (ushort*)alloc((size_t)n * DIN0 * 2);
  ushort* h_bf = (ushort*)alloc((size_t)n * DOUT * 2);
  ushort* agg_bf = (ushort*)alloc((size_t)n * DOUT * 2);
  ushort* Wt0 = (ushort*)alloc((size_t)256 * 2 * DIN0 * 2);
  ushort* Wt1 = (ushort*)alloc((size_t)256 * 2 * DOUT * 2);
  ushort* Wt2 = (ushort*)alloc((size_t)256 * 2 * DOUT * 2);

  float* out_h = (float*)d_out;
  float* out_hg = out_h + (size_t)n * DOUT;

  hipMemsetAsync(deg_cnt, 0, (size_t)n * 4, stream);
  hipMemsetAsync(gcnt, 0, (size_t)Gn * 4, stream);
  hipMemsetAsync(out_hg, 0, (size_t)Gn * DOUT * 4, stream);

  k_deg_count<<<(E + 255) / 256, 256, 0, stream>>>(edst, deg_cnt, E);
  k_deg_inv<<<(n + 255) / 256, 256, 0, stream>>>(deg_cnt, dinv, n);
  k_gcnt<<<nb, 256, 0, stream>>>(gid, gcnt, n, Gn);

  k_scan1<<<nb, 256, 0, stream>>>(deg_cnt, part, n);
  k_scan2<<<1, 256, 0, stream>>>(part, nb);
  k_scan3<<<nb, 256, 0, stream>>>(deg_cnt, part, row_ptr, cursor, n);
  k_fill<<<(E + 255) / 256, 256, 0, stream>>>(esrc, edst, cursor, col, E);

  k_cast_bf16<<<(int)(((long long)n * DIN0 / 4 + 255) / 256), 256, 0, stream>>>(
      feat, feat_bf, (long long)n * DIN0 / 4);
  k_prep_w<<<2 * DIN0, 256, 0, stream>>>(Ws0, Wn0, Wt0, DIN0);
  k_prep_w<<<2 * DOUT, 256, 0, stream>>>(Ws1, Wn1, Wt1, DOUT);
  k_prep_w<<<2 * DOUT, 256, 0, stream>>>(Ws2, Wn2, Wt2, DOUT);

  int gemm_grid = (n + 127) / 128;
  int row_grid = (n + 3) / 4;

  // ---- layer 0 ----
  k_gather<128><<<row_grid, 256, 0, stream>>>(feat_bf, row_ptr, col, dinv,
                                              agg_bf, n);
  k_gemm_ln<128, true><<<gemm_grid, 512, 0, stream>>>(
      feat_bf, agg_bf, Wt0, b0, g0, be0, h_bf, nullptr, n);

  // ---- layer 1 (h_bf in place) ----
  k_gather<256><<<row_grid, 256, 0, stream>>>(h_bf, row_ptr, col, dinv,
                                              agg_bf, n);
  k_gemm_ln<256, true><<<gemm_grid, 512, 0, stream>>>(
      h_bf, agg_bf, Wt1, b1, g1, be1, h_bf, nullptr, n);

  // ---- layer 2 -> d_out fp32 ----
  k_gather<256><<<row_grid, 256, 0, stream>>>(h_bf, row_ptr, col, dinv,
                                              agg_bf, n);
  k_gemm_ln<256, false><<<gemm_grid, 512, 0, stream>>>(
      h_bf, agg_bf, Wt2, b2, g2, be2, nullptr, out_h, n);

  // ---- readout ----
  k_readout<<<(n + 63) / 64, 256, 0, stream>>>(out_h, gid, out_hg, n);
  k_hg_scale<<<(Gn * DOUT + 255) / 256, 256, 0, stream>>>(out_hg, gcnt,
                                                          Gn * DOUT);
}

// Round 5
// 313.046 us; speedup vs baseline: 21.2779x; 1.1266x over previous
//
#include <hip/hip_runtime.h>
#include <hip/hip_bf16.h>

constexpr int DOUT = 256;

typedef __bf16 bf16x8 __attribute__((ext_vector_type(8)));
typedef float f32x4 __attribute__((ext_vector_type(4)));

__device__ inline float bf2f(ushort u) {
  return __uint_as_float((unsigned)u << 16);
}
__device__ inline ushort f2bf(float f) {
  unsigned b = __float_as_uint(f);
  return (ushort)((b + 0x7FFF + ((b >> 16) & 1)) >> 16);  // RNE
}
__device__ inline float bflo(int v) {
  return __uint_as_float((unsigned)v << 16);
}
__device__ inline float bfhi(int v) {
  return __uint_as_float((unsigned)v & 0xffff0000u);
}
__device__ inline int packbf(float a, float b) {
  return (int)((unsigned)f2bf(a) | ((unsigned)f2bf(b) << 16));
}

// bijective XCD chunk swizzle (m204)
__device__ inline int xcd_swizzle(int bid, int nwg) {
  int q = nwg >> 3, r = nwg & 7;
  int xcd = bid & 7, idx = bid >> 3;
  return (xcd < r ? xcd * (q + 1) : r * (q + 1) + (xcd - r) * q) + idx;
}

// ---------------- degree / counts ----------------
__global__ __launch_bounds__(256) void k_deg_count(const int* __restrict__ dst,
                                                   int* __restrict__ cnt, int E) {
  int t = blockIdx.x * blockDim.x + threadIdx.x;
  if (t < E) atomicAdd(&cnt[dst[t]], 1);
}

__global__ __launch_bounds__(256) void k_gcnt(const int* __restrict__ gid,
                                              int* __restrict__ cnt, int n, int G) {
  __shared__ int h[256];
  int t = threadIdx.x;
  if (t < G) h[t] = 0;
  __syncthreads();
  int i = blockIdx.x * 256 + t;
  if (i < n) atomicAdd(&h[gid[i]], 1);
  __syncthreads();
  if (t < G && h[t]) atomicAdd(&cnt[t], h[t]);
}

// ---------------- CSR build ----------------
__global__ __launch_bounds__(256) void k_scan1(const int* __restrict__ deg,
                                               int* __restrict__ part, int n) {
  int i = blockIdx.x * 256 + threadIdx.x;
  int v = (i < n) ? deg[i] : 0;
#pragma unroll
  for (int o = 32; o > 0; o >>= 1) v += __shfl_xor(v, o);
  __shared__ int s[4];
  int wave = threadIdx.x >> 6, lane = threadIdx.x & 63;
  if (lane == 0) s[wave] = v;
  __syncthreads();
  if (threadIdx.x == 0) part[blockIdx.x] = s[0] + s[1] + s[2] + s[3];
}

__global__ __launch_bounds__(256) void k_scan2(int* __restrict__ part, int nb) {
  __shared__ int s[256];
  int t = threadIdx.x;
  int v = (t < nb) ? part[t] : 0;
  s[t] = v;
  __syncthreads();
  for (int o = 1; o < 256; o <<= 1) {
    int u = (t >= o) ? s[t - o] : 0;
    __syncthreads();
    s[t] += u;
    __syncthreads();
  }
  int excl = (t == 0) ? 0 : s[t - 1];
  if (t < nb) part[t] = excl;
}

// scan3 also emits dinv (folds k_deg_inv)
__global__ __launch_bounds__(256) void k_scan3(const int* __restrict__ deg,
                                               const int* __restrict__ part,
                                               int* __restrict__ rp,
                                               int* __restrict__ cur,
                                               float* __restrict__ dinv, int n) {
  __shared__ int s[256];
  int t = threadIdx.x;
  int i = blockIdx.x * 256 + t;
  int v = (i < n) ? deg[i] : 0;
  s[t] = v;
  __syncthreads();
  for (int o = 1; o < 256; o <<= 1) {
    int u = (t >= o) ? s[t - o] : 0;
    __syncthreads();
    s[t] += u;
    __syncthreads();
  }
  int incl = s[t];
  int excl = incl - v;
  int base = part[blockIdx.x];
  if (i < n) {
    rp[i] = base + excl;
    cur[i] = base + excl;
    dinv[i] = 1.0f / (float)v;
  }
  if (i == n - 1) rp[n] = base + incl;
}

__global__ __launch_bounds__(256) void k_fill(const int* __restrict__ src,
                                              const int* __restrict__ dst,
                                              int* __restrict__ cur,
                                              int* __restrict__ col, int E) {
  int e = blockIdx.x * 256 + threadIdx.x;
  if (e < E) {
    int p = atomicAdd(&cur[dst[e]], 1);
    col[p] = src[e];
  }
}

// ---------------- cast fp32 -> bf16 ----------------
__global__ __launch_bounds__(256) void k_cast_bf16(const float* __restrict__ in,
                                                   ushort* __restrict__ out,
                                                   long long total4) {
  long long t = (long long)blockIdx.x * 256 + threadIdx.x;
  if (t >= total4) return;
  float4 v = *(const float4*)(in + t * 4);
  ushort4 o;
  o.x = f2bf(v.x); o.y = f2bf(v.y); o.z = f2bf(v.z); o.w = f2bf(v.w);
  *(ushort4*)(out + t * 4) = o;
}

// ---------------- weight prep: Wt[n][k] bf16, K = 2*DIN ----------------
__global__ __launch_bounds__(256) void k_prep_w(const float* __restrict__ Ws,
                                                const float* __restrict__ Wn,
                                                ushort* __restrict__ Wt, int DIN) {
  int t = blockIdx.x * 256 + threadIdx.x;
  int K = 2 * DIN;
  int nn = t & 255;
  int k = t >> 8;
  if (k >= K) return;
  const float* W = (k < DIN) ? (Ws + (size_t)k * 256) : (Wn + (size_t)(k - DIN) * 256);
  Wt[(size_t)nn * K + k] = f2bf(W[nn]);
}

// ---------------- CSR gather (bf16), multi-neighbor-per-wave ----------------
// DIN=256: 2 neighbors/wave (32 lanes x 8 dims each), 2-deep unroll.
// DIN=128: 4 neighbors/wave (16 lanes x 8 dims each), 2-deep unroll.
template <int DIN>
__global__ __launch_bounds__(256) void k_gather(const ushort* __restrict__ h,
                                                const int* __restrict__ rp,
                                                const int* __restrict__ col,
                                                const float* __restrict__ dinv,
                                                ushort* __restrict__ agg, int n) {
  int wg = xcd_swizzle(blockIdx.x, gridDim.x);
  int wave = threadIdx.x >> 6, lane = threadIdx.x & 63;
  int node = wg * 4 + wave;
  if (node >= n) return;
  int beg = rp[node], end = rp[node + 1];
  float s = dinv[node];
  float a[8] = {};
  if constexpr (DIN == 256) {
    int half = lane >> 5, sub = lane & 31;
    const ushort* base = h + sub * 8;
    int j = beg + half;
    for (; j + 2 < end; j += 4) {
      int c0 = col[j], c1 = col[j + 2];
      int4 v0 = *(const int4*)(base + (size_t)c0 * DIN);
      int4 v1 = *(const int4*)(base + (size_t)c1 * DIN);
      a[0] += bflo(v0.x) + bflo(v1.x);
      a[1] += bfhi(v0.x) + bfhi(v1.x);
      a[2] += bflo(v0.y) + bflo(v1.y);
      a[3] += bfhi(v0.y) + bfhi(v1.y);
      a[4] += bflo(v0.z) + bflo(v1.z);
      a[5] += bfhi(v0.z) + bfhi(v1.z);
      a[6] += bflo(v0.w) + bflo(v1.w);
      a[7] += bfhi(v0.w) + bfhi(v1.w);
    }
    for (; j < end; j += 2) {
      int4 v = *(const int4*)(base + (size_t)col[j] * DIN);
      a[0] += bflo(v.x); a[1] += bfhi(v.x);
      a[2] += bflo(v.y); a[3] += bfhi(v.y);
      a[4] += bflo(v.z); a[5] += bfhi(v.z);
      a[6] += bflo(v.w); a[7] += bfhi(v.w);
    }
#pragma unroll
    for (int d = 0; d < 8; ++d) a[d] += __shfl_xor(a[d], 32);
    if (half == 0) {
      int4 o;
      o.x = packbf(a[0] * s, a[1] * s);
      o.y = packbf(a[2] * s, a[3] * s);
      o.z = packbf(a[4] * s, a[5] * s);
      o.w = packbf(a[6] * s, a[7] * s);
      *(int4*)(agg + (size_t)node * DIN + sub * 8) = o;
    }
  } else {  // DIN == 128
    int quad = lane >> 4, sub = lane & 15;
    const ushort* base = h + sub * 8;
    int j = beg + quad;
    for (; j + 4 < end; j += 8) {
      int c0 = col[j], c1 = col[j + 4];
      int4 v0 = *(const int4*)(base + (size_t)c0 * DIN);
      int4 v1 = *(const int4*)(base + (size_t)c1 * DIN);
      a[0] += bflo(v0.x) + bflo(v1.x);
      a[1] += bfhi(v0.x) + bfhi(v1.x);
      a[2] += bflo(v0.y) + bflo(v1.y);
      a[3] += bfhi(v0.y) + bfhi(v1.y);
      a[4] += bflo(v0.z) + bflo(v1.z);
      a[5] += bfhi(v0.z) + bfhi(v1.z);
      a[6] += bflo(v0.w) + bflo(v1.w);
      a[7] += bfhi(v0.w) + bfhi(v1.w);
    }
    for (; j < end; j += 4) {
      int4 v = *(const int4*)(base + (size_t)col[j] * DIN);
      a[0] += bflo(v.x); a[1] += bfhi(v.x);
      a[2] += bflo(v.y); a[3] += bfhi(v.y);
      a[4] += bflo(v.z); a[5] += bfhi(v.z);
      a[6] += bflo(v.w); a[7] += bfhi(v.w);
    }
#pragma unroll
    for (int d = 0; d < 8; ++d) a[d] += __shfl_xor(a[d], 16);
#pragma unroll
    for (int d = 0; d < 8; ++d) a[d] += __shfl_xor(a[d], 32);
    if (quad == 0) {
      int4 o;
      o.x = packbf(a[0] * s, a[1] * s);
      o.y = packbf(a[2] * s, a[3] * s);
      o.z = packbf(a[4] * s, a[5] * s);
      o.w = packbf(a[6] * s, a[7] * s);
      *(int4*)(agg + (size_t)node * DIN + sub * 8) = o;
    }
  }
}

// ---------------- fused GEMM + bias + LayerNorm + ELU ----------------
// Block: 128 rows x 256 cols, 512 threads = 8 waves (2 row x 4 col).
template <int DIN, bool BF16OUT>
__global__ __launch_bounds__(512) void k_gemm_ln(
    const ushort* __restrict__ A0, const ushort* __restrict__ A1,
    const ushort* __restrict__ Wt, const float* __restrict__ bias,
    const float* __restrict__ g, const float* __restrict__ be,
    ushort* __restrict__ outB, float* __restrict__ outF, int n) {
  constexpr int K = 2 * DIN;
  __shared__ ushort As[128 * 32];
  __shared__ ushort Bs[256 * 32];
  __shared__ float redS[4][128];
  __shared__ float redQ[4][128];
  const int tid = threadIdx.x;
  const int lane = tid & 63, wid = tid >> 6;
  const int wr = wid >> 2, wc = wid & 3;
  const int m0 = blockIdx.x * 128;
  const int fr = lane & 15, kg = lane >> 4;
  const int s_row = tid >> 2, s_c = tid & 3;

  f32x4 acc[4][4] = {};

  for (int k0 = 0; k0 < K; k0 += 32) {
    const ushort* Asrc = (k0 < DIN) ? A0 : A1;
    const int ak = (k0 < DIN) ? k0 : (k0 - DIN);
    {
      int grow = m0 + s_row;
      int4 v = make_int4(0, 0, 0, 0);
      if (grow < n) v = *(const int4*)(Asrc + (size_t)grow * DIN + ak + s_c * 8);
      *(int4*)&As[s_row * 32 + ((s_c ^ (s_row & 3)) * 8)] = v;
      int4 w0 = *(const int4*)(Wt + (size_t)s_row * K + k0 + s_c * 8);
      *(int4*)&Bs[s_row * 32 + ((s_c ^ (s_row & 3)) * 8)] = w0;
      int r2 = s_row + 128;
      int4 w1 = *(const int4*)(Wt + (size_t)r2 * K + k0 + s_c * 8);
      *(int4*)&Bs[r2 * 32 + ((s_c ^ (r2 & 3)) * 8)] = w1;
    }
    __syncthreads();
    bf16x8 af[4], bb[4];
#pragma unroll
    for (int mi = 0; mi < 4; ++mi) {
      int row = wr * 64 + mi * 16 + fr;
      af[mi] = *(const bf16x8*)&As[row * 32 + ((kg ^ (row & 3)) * 8)];
    }
#pragma unroll
    for (int ni = 0; ni < 4; ++ni) {
      int row = wc * 64 + ni * 16 + fr;
      bb[ni] = *(const bf16x8*)&Bs[row * 32 + ((kg ^ (row & 3)) * 8)];
    }
#pragma unroll
    for (int mi = 0; mi < 4; ++mi)
#pragma unroll
      for (int ni = 0; ni < 4; ++ni)
        acc[mi][ni] = __builtin_amdgcn_mfma_f32_16x16x32_bf16(af[mi], bb[ni],
                                                              acc[mi][ni], 0, 0, 0);
    __syncthreads();
  }

  float bv[4], gv[4], ev[4];
#pragma unroll
  for (int ni = 0; ni < 4; ++ni) {
    int c = wc * 64 + ni * 16 + fr;
    bv[ni] = bias[c];
    gv[ni] = g[c];
    ev[ni] = be[c];
  }
#pragma unroll
  for (int mi = 0; mi < 4; ++mi)
#pragma unroll
    for (int ni = 0; ni < 4; ++ni)
#pragma unroll
      for (int j = 0; j < 4; ++j) acc[mi][ni][j] += bv[ni];

#pragma unroll
  for (int mi = 0; mi < 4; ++mi) {
#pragma unroll
    for (int j = 0; j < 4; ++j) {
      float s = 0.f, q = 0.f;
#pragma unroll
      for (int ni = 0; ni < 4; ++ni) {
        float a = acc[mi][ni][j];
        s += a;
        q += a * a;
      }
#pragma unroll
      for (int o = 1; o < 16; o <<= 1) {
        s += __shfl_xor(s, o);
        q += __shfl_xor(q, o);
      }
      if (fr == 0) {
        int lr = wr * 64 + mi * 16 + kg * 4 + j;
        redS[wc][lr] = s;
        redQ[wc][lr] = q;
      }
    }
  }
  __syncthreads();
#pragma unroll
  for (int mi = 0; mi < 4; ++mi) {
#pragma unroll
    for (int j = 0; j < 4; ++j) {
      int lr = wr * 64 + mi * 16 + kg * 4 + j;
      int r = m0 + lr;
      if (r >= n) continue;
      float tot = redS[0][lr] + redS[1][lr] + redS[2][lr] + redS[3][lr];
      float tq = redQ[0][lr] + redQ[1][lr] + redQ[2][lr] + redQ[3][lr];
      float mean = tot * (1.0f / 256.0f);
      float var = tq * (1.0f / 256.0f) - mean * mean;
      float rstd = rsqrtf(var + 1e-5f);
#pragma unroll
      for (int ni = 0; ni < 4; ++ni) {
        int c = wc * 64 + ni * 16 + fr;
        float val = (acc[mi][ni][j] - mean) * rstd * gv[ni] + ev[ni];
        val = val > 0.f ? val : expm1f(val);
        if constexpr (BF16OUT)
          outB[(size_t)r * DOUT + c] = f2bf(val);
        else
          outF[(size_t)r * DOUT + c] = val;
      }
    }
  }
}

// ---------------- per-graph mean readout ----------------
__global__ __launch_bounds__(256) void k_readout(const float* __restrict__ h,
                                                 const int* __restrict__ gid,
                                                 float* __restrict__ hg, int n) {
  int start = blockIdx.x * 64;
  int end = min(start + 64, n);
  int c = threadIdx.x;
  float acc = 0.f;
  int cur = gid[start];
  for (int i = start; i < end; ++i) {
    int g = gid[i];
    if (g != cur) {
      atomicAdd(&hg[(size_t)cur * DOUT + c], acc);
      acc = 0.f;
      cur = g;
    }
    acc += h[(size_t)i * DOUT + c];
  }
  atomicAdd(&hg[(size_t)cur * DOUT + c], acc);
}

__global__ __launch_bounds__(256) void k_hg_scale(float* __restrict__ hg,
                                                  const int* __restrict__ cnt,
                                                  int total) {
  int t = blockIdx.x * blockDim.x + threadIdx.x;
  if (t < total) hg[t] *= 1.0f / (float)cnt[t >> 8];
}

extern "C" void kernel_launch(void* const* d_in, const int* in_sizes, int n_in,
                              void* d_out, int out_size, void* d_ws, size_t ws_size,
                              hipStream_t stream) {
  const float* feat = (const float*)d_in[0];
  const int* esrc = (const int*)d_in[1];
  const int* edst = (const int*)d_in[2];
  const int* gid = (const int*)d_in[3];
  const float* Ws0 = (const float*)d_in[4];
  const float* Wn0 = (const float*)d_in[5];
  const float* b0 = (const float*)d_in[6];
  const float* g0 = (const float*)d_in[7];
  const float* be0 = (const float*)d_in[8];
  const float* Ws1 = (const float*)d_in[9];
  const float* Wn1 = (const float*)d_in[10];
  const float* b1 = (const float*)d_in[11];
  const float* g1 = (const float*)d_in[12];
  const float* be1 = (const float*)d_in[13];
  const float* Ws2 = (const float*)d_in[14];
  const float* Wn2 = (const float*)d_in[15];
  const float* b2 = (const float*)d_in[16];
  const float* g2 = (const float*)d_in[17];
  const float* be2 = (const float*)d_in[18];

  const int E = in_sizes[1];
  const int n = in_sizes[3];
  const int DIN0 = in_sizes[0] / n;             // 128
  const int Gn = (out_size - n * DOUT) / DOUT;  // 16
  const int nb = (n + 255) / 256;

  char* ws = (char*)d_ws;
  size_t off = 0;
  auto alloc = [&](size_t bytes) -> void* {
    void* p = ws + off;
    off += (bytes + 255) & ~(size_t)255;
    return p;
  };
  int* deg_cnt = (int*)alloc((size_t)n * 4);
  float* dinv = (float*)alloc((size_t)n * 4);
  int* gcnt = (int*)alloc((size_t)Gn * 4);
  int* row_ptr = (int*)alloc((size_t)(n + 1) * 4);
  int* cursor = (int*)alloc((size_t)n * 4);
  int* part = (int*)alloc((size_t)nb * 4);
  int* col = (int*)alloc((size_t)E * 4);
  ushort* feat_bf = (ushort*)alloc((size_t)n * DIN0 * 2);
  ushort* h_bf = (ushort*)alloc((size_t)n * DOUT * 2);
  ushort* agg_bf = (ushort*)alloc((size_t)n * DOUT * 2);
  ushort* Wt0 = (ushort*)alloc((size_t)256 * 2 * DIN0 * 2);
  ushort* Wt1 = (ushort*)alloc((size_t)256 * 2 * DOUT * 2);
  ushort* Wt2 = (ushort*)alloc((size_t)256 * 2 * DOUT * 2);

  float* out_h = (float*)d_out;
  float* out_hg = out_h + (size_t)n * DOUT;

  hipMemsetAsync(deg_cnt, 0, (size_t)n * 4, stream);
  hipMemsetAsync(gcnt, 0, (size_t)Gn * 4, stream);
  hipMemsetAsync(out_hg, 0, (size_t)Gn * DOUT * 4, stream);

  k_deg_count<<<(E + 255) / 256, 256, 0, stream>>>(edst, deg_cnt, E);
  k_gcnt<<<nb, 256, 0, stream>>>(gid, gcnt, n, Gn);

  k_scan1<<<nb, 256, 0, stream>>>(deg_cnt, part, n);
  k_scan2<<<1, 256, 0, stream>>>(part, nb);
  k_scan3<<<nb, 256, 0, stream>>>(deg_cnt, part, row_ptr, cursor, dinv, n);
  k_fill<<<(E + 255) / 256, 256, 0, stream>>>(esrc, edst, cursor, col, E);

  k_cast_bf16<<<(int)(((long long)n * DIN0 / 4 + 255) / 256), 256, 0, stream>>>(
      feat, feat_bf, (long long)n * DIN0 / 4);
  k_prep_w<<<2 * DIN0, 256, 0, stream>>>(Ws0, Wn0, Wt0, DIN0);
  k_prep_w<<<2 * DOUT, 256, 0, stream>>>(Ws1, Wn1, Wt1, DOUT);
  k_prep_w<<<2 * DOUT, 256, 0, stream>>>(Ws2, Wn2, Wt2, DOUT);

  int gemm_grid = (n + 127) / 128;
  int row_grid = (n + 3) / 4;

  // ---- layer 0 ----
  k_gather<128><<<row_grid, 256, 0, stream>>>(feat_bf, row_ptr, col, dinv,
                                              agg_bf, n);
  k_gemm_ln<128, true><<<gemm_grid, 512, 0, stream>>>(
      feat_bf, agg_bf, Wt0, b0, g0, be0, h_bf, nullptr, n);

  // ---- layer 1 (h_bf in place) ----
  k_gather<256><<<row_grid, 256, 0, stream>>>(h_bf, row_ptr, col, dinv,
                                              agg_bf, n);
  k_gemm_ln<256, true><<<gemm_grid, 512, 0, stream>>>(
      h_bf, agg_bf, Wt1, b1, g1, be1, h_bf, nullptr, n);

  // ---- layer 2 -> d_out fp32 ----
  k_gather<256><<<row_grid, 256, 0, stream>>>(h_bf, row_ptr, col, dinv,
                                              agg_bf, n);
  k_gemm_ln<256, false><<<gemm_grid, 512, 0, stream>>>(
      h_bf, agg_bf, Wt2, b2, g2, be2, nullptr, out_h, n);

  // ---- readout ----
  k_readout<<<(n + 63) / 64, 256, 0, stream>>>(out_h, gid, out_hg, n);
  k_hg_scale<<<(Gn * DOUT + 255) / 256, 256, 0, stream>>>(out_hg, gcnt,
                                                          Gn * DOUT);
}